// Round 1
// baseline (4433.347 us; speedup 1.0000x reference)
//
#include <hip/hip_runtime.h>
#include <math.h>

#define NB   4096
#define NIN  768
#define NLAT 24576

#define BM 128
#define BN 128
#define BK 16
#define LDT 132   // padded LDS stride: 2-way max bank aliasing

#define HBINS    4096
#define CAND_CAP 256
#define BAND_CAP 128
#define MAIN_CAP 64
#define AUX_CAP  1024

__device__ __forceinline__ unsigned fkey(float f) {
  unsigned u = __float_as_uint(f);
  return u ^ ((unsigned)((int)u >> 31) | 0x80000000u);  // monotone total order
}
__device__ __forceinline__ float keyinv(unsigned u) {
  unsigned s = (u & 0x80000000u) ? (u ^ 0x80000000u) : ~u;
  return __uint_as_float(s);
}

// ---------------- W_dec [NIN][NLAT] -> Wt [NLAT][NIN] ----------------
__global__ __launch_bounds__(256) void k_transpose(const float* __restrict__ src,
                                                   float* __restrict__ dst) {
  __shared__ float tile[32][33];
  int bx = blockIdx.x * 32;  // NLAT
  int by = blockIdx.y * 32;  // NIN
  int tx = threadIdx.x, ty = threadIdx.y;
  for (int i = ty; i < 32; i += 8)
    tile[i][tx] = src[(size_t)(by + i) * NLAT + bx + tx];
  __syncthreads();
  for (int i = ty; i < 32; i += 8)
    dst[(size_t)(bx + i) * NIN + by + tx] = tile[tx][i];
}

// ---------------- alpha_pre = (x - b) @ W_enc^T + b_enc --------------
__global__ __launch_bounds__(256) void k_encgemm(
    const float* __restrict__ x, const float* __restrict__ bvec,
    const float* __restrict__ We, const float* __restrict__ be,
    float* __restrict__ apre) {
  __shared__ float As[BK][LDT];
  __shared__ float Bs[BK][LDT];
  const int t = threadIdx.x;
  const int m0 = blockIdx.x * BM;
  const int n0 = blockIdx.y * BN;
  const int lane = t & 63, wave = t >> 6;
  const int cn = ((wave & 1) * 8 + (lane & 7)) * 8;
  const int cm = ((wave >> 1) * 8 + (lane >> 3)) * 8;
  float acc[8][8] = {};
  const float* xb = x + (size_t)m0 * NIN;
  const float* wb = We + (size_t)n0 * NIN;
  for (int k0 = 0; k0 < NIN; k0 += BK) {
#pragma unroll
    for (int i = 0; i < 2; ++i) {
      int e = t + i * 256;
      int row = e >> 2, q = e & 3;
      float4 bv = *(const float4*)(bvec + k0 + q * 4);
      float4 av = *(const float4*)(xb + (size_t)row * NIN + k0 + q * 4);
      av.x -= bv.x; av.y -= bv.y; av.z -= bv.z; av.w -= bv.w;
      As[q * 4 + 0][row] = av.x; As[q * 4 + 1][row] = av.y;
      As[q * 4 + 2][row] = av.z; As[q * 4 + 3][row] = av.w;
      float4 wv = *(const float4*)(wb + (size_t)row * NIN + k0 + q * 4);
      Bs[q * 4 + 0][row] = wv.x; Bs[q * 4 + 1][row] = wv.y;
      Bs[q * 4 + 2][row] = wv.z; Bs[q * 4 + 3][row] = wv.w;
    }
    __syncthreads();
#pragma unroll
    for (int kk = 0; kk < BK; ++kk) {
      float a0[8], b0[8];
      *(float4*)&a0[0] = *(const float4*)&As[kk][cm];
      *(float4*)&a0[4] = *(const float4*)&As[kk][cm + 4];
      *(float4*)&b0[0] = *(const float4*)&Bs[kk][cn];
      *(float4*)&b0[4] = *(const float4*)&Bs[kk][cn + 4];
#pragma unroll
      for (int i = 0; i < 8; ++i)
#pragma unroll
        for (int j = 0; j < 8; ++j)
          acc[i][j] = fmaf(a0[i], b0[j], acc[i][j]);
    }
    __syncthreads();
  }
  float bb[8];
  *(float4*)&bb[0] = *(const float4*)(be + n0 + cn);
  *(float4*)&bb[4] = *(const float4*)(be + n0 + cn + 4);
#pragma unroll
  for (int i = 0; i < 8; ++i) {
    float4 v0 = make_float4(acc[i][0] + bb[0], acc[i][1] + bb[1],
                            acc[i][2] + bb[2], acc[i][3] + bb[3]);
    float4 v1 = make_float4(acc[i][4] + bb[4], acc[i][5] + bb[5],
                            acc[i][6] + bb[6], acc[i][7] + bb[7]);
    float* orow = apre + (size_t)(m0 + cm + i) * NLAT + n0 + cn;
    *(float4*)orow = v0;
    *(float4*)(orow + 4) = v1;
  }
}

// find boundary bin for rank kk over 4096-bin hist; returns bin, count strictly
// above bin, and clamped kk. Uniform control flow; uses csuf + tmp (shared).
__device__ void find_bin(int* hist, unsigned* csuf, int* tmp, int t, int kk,
                         int& bin, int& above, int& kke) {
  unsigned c = 0;
#pragma unroll
  for (int i = 0; i < 16; ++i) c += (unsigned)hist[t * 16 + i];
  csuf[t] = c;
  __syncthreads();
  for (int off = 1; off < 256; off <<= 1) {
    unsigned add = (t + off < 256) ? csuf[t + off] : 0u;
    __syncthreads();
    csuf[t] += add;
    __syncthreads();
  }
  int total = (int)csuf[0];
  int k2 = kk < total ? kk : total;
  kke = k2;
  if (k2 <= 0) { bin = -1; above = 0; return; }
  if (csuf[t] >= (unsigned)k2 && (t == 255 || csuf[t + 1] < (unsigned)k2))
    tmp[0] = t;
  __syncthreads();
  int cstar = tmp[0];
  if (t == 0) {
    int ab = (cstar == 255) ? 0 : (int)csuf[cstar + 1];
    int bb = cstar * 16 + 15;
    for (int i2 = 15; i2 >= 0; --i2) {
      int h = hist[cstar * 16 + i2];
      if (ab + h >= k2) { bb = cstar * 16 + i2; break; }
      ab += h;
    }
    tmp[1] = bb; tmp[2] = ab;
  }
  __syncthreads();
  bin = tmp[1]; above = tmp[2];
}

// ------------- per-row: topk select (aux + main), write alpha/mask, decode ----
__global__ __launch_bounds__(256) void k_select(
    const float* __restrict__ x, const float* __restrict__ bvec,
    const float* __restrict__ We, const float* __restrict__ be,
    const int* __restrict__ miss, const int* __restrict__ kptr,
    const int* __restrict__ akptr,
    float* __restrict__ alpha, float* __restrict__ apre,
    const float* __restrict__ Wt, const float* __restrict__ Wd,
    float* __restrict__ xhat, float* __restrict__ auxo) {
  const int t = threadIdx.x;
  const int r = blockIdx.x;
  const float* rowv = apre + (size_t)r * NLAT;

  __shared__ int hist[HBINS];
  __shared__ unsigned csuf[256];
  __shared__ int tmp4[4];
  __shared__ unsigned s_cnt;
  __shared__ int candIdx[CAND_CAP];
  __shared__ unsigned candU[CAND_CAP];
  __shared__ unsigned s_uk;
  __shared__ float s_hi, s_lo;
  __shared__ unsigned s_nab, s_bc;
  __shared__ int bandIdx[BAND_CAP];
  __shared__ double bandV[BAND_CAP];
  __shared__ unsigned char bandSel[BAND_CAP];
  __shared__ double red[256];
  __shared__ int sIdx[MAIN_CAP];
  __shared__ float sVal[MAIN_CAP];
  __shared__ int aIdx[AUX_CAP];
  __shared__ float aVal[AUX_CAP];
  __shared__ int s_mainCnt, s_auxCnt;

  int kmain = kptr[0];  kmain = kmain < MAIN_CAP ? kmain : MAIN_CAP;
  int kaux  = akptr[0]; kaux  = kaux  < AUX_CAP  ? kaux  : AUX_CAP;

  // pass 0 = AUX (eligible: miss>=1), pass 1 = MAIN (all). Main state stays
  // live after the loop for the alpha/mask write.
  for (int pass = 0; pass < 2; ++pass) {
    const bool isAux = (pass == 0);
    const int kreq = isAux ? kaux : kmain;

    // ---- level-1 histogram (bits 31:20 of sortable key)
    for (int i = t; i < HBINS; i += 256) hist[i] = 0;
    __syncthreads();
    for (int j = t; j < NLAT; j += 256) {
      if (isAux && miss[j] < 1) continue;
      atomicAdd(&hist[fkey(rowv[j]) >> 20], 1);
    }
    __syncthreads();
    int b1, cab1, kke;
    find_bin(hist, csuf, tmp4, t, kreq, b1, cab1, kke);
    if (kke <= 0) {
      if (t == 0) {
        s_hi = INFINITY; s_lo = INFINITY; s_bc = 0;
        if (isAux) s_auxCnt = 0; else s_mainCnt = 0;
      }
      __syncthreads();
      continue;
    }
    int need1 = kke - cab1;

    // ---- level-2 histogram (bits 19:8) within bin b1
    for (int i = t; i < HBINS; i += 256) hist[i] = 0;
    __syncthreads();
    for (int j = t; j < NLAT; j += 256) {
      if (isAux && miss[j] < 1) continue;
      unsigned u = fkey(rowv[j]);
      if ((int)(u >> 20) == b1) atomicAdd(&hist[(u >> 8) & 0xFFF], 1);
    }
    __syncthreads();
    int b2, cab2, dkke;
    find_bin(hist, csuf, tmp4, t, need1, b2, cab2, dkke);
    int need2 = need1 - cab2;
    unsigned P = ((unsigned)b1 << 12) | (unsigned)b2;

    // ---- collect candidates in boundary 256-ulp bin, exact-rank the kth key
    if (t == 0) s_cnt = 0;
    __syncthreads();
    for (int j = t; j < NLAT; j += 256) {
      if (isAux && miss[j] < 1) continue;
      unsigned u = fkey(rowv[j]);
      if ((u >> 8) == P) {
        unsigned p = atomicAdd(&s_cnt, 1u);
        if (p < CAND_CAP) { candIdx[p] = j; candU[p] = u; }
      }
    }
    __syncthreads();
    int cc = s_cnt < CAND_CAP ? (int)s_cnt : CAND_CAP;
    if (t < cc) {
      unsigned ui = candU[t]; int ii = candIdx[t];
      int rank = 0;
      for (int q = 0; q < cc; ++q) {
        unsigned uq = candU[q];
        if (uq > ui || (uq == ui && candIdx[q] < ii)) ++rank;
      }
      if (rank == need2 - 1) s_uk = ui;   // kth largest f32 value's key
    }
    __syncthreads();

    // ---- f64 boundary refinement band around Vk
    float Vk = keyinv(s_uk);
    float eps = fmaxf(1e-4f, fabsf(Vk) * 1e-4f);
    if (t == 0) { s_hi = Vk + eps; s_lo = Vk - eps; s_nab = 0; s_bc = 0; }
    __syncthreads();
    float hi = s_hi, lo = s_lo;
    for (int j = t; j < NLAT; j += 256) {
      if (isAux && miss[j] < 1) continue;
      float v = rowv[j];
      if (v > hi) atomicAdd(&s_nab, 1u);
      else if (v >= lo) {
        unsigned p = atomicAdd(&s_bc, 1u);
        if (p < BAND_CAP) bandIdx[p] = j;
      }
    }
    __syncthreads();
    int bc = s_bc < BAND_CAP ? (int)s_bc : BAND_CAP;
    int needB = kke - (int)s_nab;
    const float* xrow = x + (size_t)r * NIN;
    for (int m = 0; m < bc; ++m) {
      double part = 0.0;
      const float* wrow = We + (size_t)bandIdx[m] * NIN;
      for (int kx = t; kx < NIN; kx += 256)
        part += ((double)xrow[kx] - (double)bvec[kx]) * (double)wrow[kx];
      red[t] = part;
      __syncthreads();
      for (int s = 128; s > 0; s >>= 1) {
        if (t < s) red[t] += red[t + s];
        __syncthreads();
      }
      if (t == 0) bandV[m] = red[0] + (double)be[bandIdx[m]];
      __syncthreads();
    }
    if (t < bc) {
      double vi = bandV[t]; int ii = bandIdx[t];
      double tie = fabs((double)Vk) * 4e-8 + 1e-12;  // sub-f32-ulp => idx order
      int rank = 0;
      for (int q = 0; q < bc; ++q) {
        double d = bandV[q] - vi;
        bool g = (fabs(d) <= tie) ? (bandIdx[q] < ii) : (d > 0.0);
        if (g) ++rank;
      }
      bandSel[t] = (rank < needB) ? 1 : 0;
    }
    __syncthreads();

    // ---- emit selected (idx,val) to LDS list
    if (t == 0) s_cnt = 0;
    __syncthreads();
    for (int j = t; j < NLAT; j += 256) {
      if (isAux && miss[j] < 1) continue;
      float v = rowv[j];
      bool sel = (v > hi);
      if (!sel && v >= lo) {
        for (int m2 = 0; m2 < bc; ++m2)
          if (bandIdx[m2] == j) { sel = bandSel[m2] != 0; break; }
      }
      if (sel) {
        unsigned p = atomicAdd(&s_cnt, 1u);
        if (isAux) { if (p < (unsigned)AUX_CAP)  { aIdx[p] = j; aVal[p] = v; } }
        else       { if (p < (unsigned)MAIN_CAP) { sIdx[p] = j; sVal[p] = v; } }
      }
    }
    __syncthreads();
    if (t == 0) {
      int c = (int)s_cnt;
      if (isAux) s_auxCnt = c < AUX_CAP ? c : AUX_CAP;
      else s_mainCnt = c < MAIN_CAP ? c : MAIN_CAP;
    }
    __syncthreads();
  }

  // ---- write alpha + fired_mask (overwrites alpha_pre; read-then-write per elem)
  {
    float hi = s_hi, lo = s_lo;
    int bc = s_bc < BAND_CAP ? (int)s_bc : BAND_CAP;
    for (int j = t; j < NLAT; j += 256) {
      float v = rowv[j];
      bool sel = (v > hi);
      if (!sel && v >= lo) {
        for (int m2 = 0; m2 < bc; ++m2)
          if (bandIdx[m2] == j) { sel = bandSel[m2] != 0; break; }
      }
      alpha[(size_t)r * NLAT + j] = sel ? v : 0.0f;
      apre[(size_t)r * NLAT + j] = (sel && v != 0.0f) ? 1.0f : 0.0f;
    }
  }
  __syncthreads();

  // ---- decode: x_hat = sum sel val * W_dec[:,idx] + b ; same for aux
  int kc = s_mainCnt, ac = s_auxCnt;
  float m0v = bvec[t], m1v = bvec[t + 256], m2v = bvec[t + 512];
  float a0v = m0v, a1v = m1v, a2v = m2v;
  if (Wt) {
    for (int i = 0; i < kc; ++i) {
      const float* wr = Wt + (size_t)sIdx[i] * NIN;
      float v = sVal[i];
      m0v = fmaf(v, wr[t], m0v);
      m1v = fmaf(v, wr[t + 256], m1v);
      m2v = fmaf(v, wr[t + 512], m2v);
    }
#pragma unroll 4
    for (int i = 0; i < ac; ++i) {
      const float* wr = Wt + (size_t)aIdx[i] * NIN;
      float v = aVal[i];
      a0v = fmaf(v, wr[t], a0v);
      a1v = fmaf(v, wr[t + 256], a1v);
      a2v = fmaf(v, wr[t + 512], a2v);
    }
  } else {  // fallback: strided gather straight from W_dec
    for (int i = 0; i < kc; ++i) {
      float v = sVal[i]; int ix = sIdx[i];
      m0v = fmaf(v, Wd[(size_t)t * NLAT + ix], m0v);
      m1v = fmaf(v, Wd[(size_t)(t + 256) * NLAT + ix], m1v);
      m2v = fmaf(v, Wd[(size_t)(t + 512) * NLAT + ix], m2v);
    }
    for (int i = 0; i < ac; ++i) {
      float v = aVal[i]; int ix = aIdx[i];
      a0v = fmaf(v, Wd[(size_t)t * NLAT + ix], a0v);
      a1v = fmaf(v, Wd[(size_t)(t + 256) * NLAT + ix], a1v);
      a2v = fmaf(v, Wd[(size_t)(t + 512) * NLAT + ix], a2v);
    }
  }
  xhat[(size_t)r * NIN + t] = m0v;
  xhat[(size_t)r * NIN + t + 256] = m1v;
  xhat[(size_t)r * NIN + t + 512] = m2v;
  auxo[(size_t)r * NIN + t] = a0v;
  auxo[(size_t)r * NIN + t + 256] = a1v;
  auxo[(size_t)r * NIN + t + 512] = a2v;
}

extern "C" void kernel_launch(void* const* d_in, const int* in_sizes, int n_in,
                              void* d_out, int out_size, void* d_ws, size_t ws_size,
                              hipStream_t stream) {
  const float* x  = (const float*)d_in[0];
  const float* bv = (const float*)d_in[1];
  const float* We = (const float*)d_in[2];
  const float* be = (const float*)d_in[3];
  const float* Wd = (const float*)d_in[4];
  const int* miss = (const int*)d_in[5];
  const int* kp   = (const int*)d_in[6];
  const int* akp  = (const int*)d_in[7];

  float* out   = (float*)d_out;
  float* xhat  = out;                          // [4096 x 768]
  float* alpha = out + (size_t)3145728;        // [4096 x 24576]
  float* apre  = out + (size_t)103809024;      // fired_mask region; alpha_pre scratch
  float* auxo  = out + (size_t)204472320;      // [4096 x 768]

  size_t wtBytes = (size_t)NLAT * NIN * sizeof(float);
  float* Wt = (ws_size >= wtBytes) ? (float*)d_ws : nullptr;

  if (Wt)
    k_transpose<<<dim3(NLAT / 32, NIN / 32), dim3(32, 8), 0, stream>>>(Wd, Wt);
  k_encgemm<<<dim3(NB / BM, NLAT / BN), 256, 0, stream>>>(x, bv, We, be, apre);
  k_select<<<NB, 256, 0, stream>>>(x, bv, We, be, miss, kp, akp,
                                   alpha, apre, Wt, Wd, xhat, auxo);
}

// Round 2
// 3662.942 us; speedup vs baseline: 1.2103x; 1.2103x over previous
//
#include <hip/hip_runtime.h>
#include <math.h>

#define NB   4096
#define NIN  768
#define NLAT 24576
#define K2   2304   // [Ah|Al|Ah] x [Bh|Bh|Bl]
#define KT2  36     // K2/64

// f32 fallback GEMM tiling
#define BM 128
#define BN 128
#define BK 16
#define LDT 132

#define HBINS    4096
#define CAND_CAP 512
#define BAND_CAP 64
#define MAIN_CAP 64
#define AUX_CAP  1024
#define SEL_T    1024

typedef __bf16 bf16x8 __attribute__((ext_vector_type(8)));
typedef __bf16 bf16x2 __attribute__((ext_vector_type(2)));
typedef float  f32x4  __attribute__((ext_vector_type(4)));

__device__ __forceinline__ unsigned fkey(float f) {
  unsigned u = __float_as_uint(f);
  return u ^ ((unsigned)((int)u >> 31) | 0x80000000u);  // monotone total order
}
__device__ __forceinline__ float keyinv(unsigned u) {
  unsigned s = (u & 0x80000000u) ? (u ^ 0x80000000u) : ~u;
  return __uint_as_float(s);
}

#define GLOAD16(g, l) __builtin_amdgcn_global_load_lds( \
    (const __attribute__((address_space(1))) unsigned int*)(g), \
    (__attribute__((address_space(3))) unsigned int*)(l), 16, 0, 0)

// ---------------- W_dec [NIN][NLAT] -> Wt [NLAT][NIN] (bf16) ----------------
__global__ __launch_bounds__(256) void k_transpose(const float* __restrict__ src,
                                                   __bf16* __restrict__ dst) {
  __shared__ float tile[32][33];
  int bx = blockIdx.x * 32;  // NLAT
  int by = blockIdx.y * 32;  // NIN
  int tx = threadIdx.x, ty = threadIdx.y;
  for (int i = ty; i < 32; i += 8)
    tile[i][tx] = src[(size_t)(by + i) * NLAT + bx + tx];
  __syncthreads();
  for (int i = ty; i < 32; i += 8)
    dst[(size_t)(bx + i) * NIN + by + tx] = (__bf16)tile[tx][i];
}

// ---- pack (x-b) into A2 tiles [mt][kt][128][64], pre-swizzled LDS image ----
// element at tile byte (r*128 + c) holds k-byte (c ^ ((r&7)<<4))
__global__ __launch_bounds__(256) void k_pack_a(const float* __restrict__ x,
    const float* __restrict__ bvec, __bf16* __restrict__ A2) {
  const int mt = blockIdx.x, kt = blockIdx.y, t = threadIdx.x;
  __bf16* out = A2 + (((size_t)mt * KT2 + kt) << 13);
#pragma unroll
  for (int i = 0; i < 32; ++i) {
    int idx = i * 256 + t;
    int r = idx >> 6, c2 = idx & 63;
    int kk = c2 ^ ((r & 7) << 3);
    int kg = kt * 64 + kk;
    int k = kg >= 1536 ? kg - 1536 : (kg >= 768 ? kg - 768 : kg);
    bool lo = (kg >= 768 && kg < 1536);               // A = [Ah | Al | Ah]
    float v = x[(size_t)(mt * 128 + r) * NIN + k] - bvec[k];
    __bf16 h = (__bf16)v;
    out[idx] = lo ? (__bf16)(v - (float)h) : h;
  }
}

__global__ __launch_bounds__(256) void k_pack_b(const float* __restrict__ We,
    __bf16* __restrict__ B2) {
  const int nt = blockIdx.x, kt = blockIdx.y, t = threadIdx.x;
  __bf16* out = B2 + (((size_t)nt * KT2 + kt) << 13);
#pragma unroll
  for (int i = 0; i < 32; ++i) {
    int idx = i * 256 + t;
    int r = idx >> 6, c2 = idx & 63;
    int kk = c2 ^ ((r & 7) << 3);
    int kg = kt * 64 + kk;
    int k = kg >= 1536 ? kg - 1536 : (kg >= 768 ? kg - 768 : kg);
    bool lo = (kg >= 1536);                           // B = [Bh | Bh | Bl]
    float v = We[(size_t)(nt * 128 + r) * NIN + k];
    __bf16 h = (__bf16)v;
    out[idx] = lo ? (__bf16)(v - (float)h) : h;
  }
}

// ---------------- bf16 MFMA GEMM: apre = A2 @ B2^T + be ----------------
__global__ __launch_bounds__(256) void k_gemm_bf16(
    const __bf16* __restrict__ A2, const __bf16* __restrict__ B2,
    const float* __restrict__ be, float* __restrict__ apre) {
  __shared__ char sA[16384];
  __shared__ char sB[16384];
  const int t = threadIdx.x;
  const int lane = t & 63, wave = t >> 6;
  const int mt = blockIdx.x, nt = blockIdx.y;
  const int wm = wave >> 1, wn = wave & 1;

  int aoff[4][2], boff[4][2];
#pragma unroll
  for (int f = 0; f < 4; ++f) {
    int ra = wm * 64 + f * 16 + (lane & 15);
    int rb = wn * 64 + f * 16 + (lane & 15);
#pragma unroll
    for (int kk = 0; kk < 2; ++kk) {
      int c = kk * 64 + (lane >> 4) * 16;
      aoff[f][kk] = ra * 128 + (c ^ ((ra & 7) << 4));
      boff[f][kk] = rb * 128 + (c ^ ((rb & 7) << 4));
    }
  }
  f32x4 acc[4][4] = {};
  const char* gA = (const char*)(A2 + (((size_t)mt * KT2) << 13));
  const char* gB = (const char*)(B2 + (((size_t)nt * KT2) << 13));
  for (int kt = 0; kt < KT2; ++kt) {
    const char* tA = gA + ((size_t)kt << 14);
    const char* tB = gB + ((size_t)kt << 14);
#pragma unroll
    for (int i = 0; i < 4; ++i) {
      int chunk = (i * 4 + wave) * 1024;
      GLOAD16(tA + chunk + lane * 16, sA + chunk);
      GLOAD16(tB + chunk + lane * 16, sB + chunk);
    }
    __syncthreads();
#pragma unroll
    for (int kk = 0; kk < 2; ++kk) {
      bf16x8 a[4], b[4];
#pragma unroll
      for (int f = 0; f < 4; ++f) {
        a[f] = *(const bf16x8*)(sA + aoff[f][kk]);
        b[f] = *(const bf16x8*)(sB + boff[f][kk]);
      }
#pragma unroll
      for (int mi = 0; mi < 4; ++mi)
#pragma unroll
        for (int ni = 0; ni < 4; ++ni)
          acc[mi][ni] = __builtin_amdgcn_mfma_f32_16x16x32_bf16(a[mi], b[ni], acc[mi][ni], 0, 0, 0);
    }
    __syncthreads();
  }
  const int m0 = mt * 128 + wm * 64, n0 = nt * 128 + wn * 64;
#pragma unroll
  for (int ni = 0; ni < 4; ++ni) {
    int n = n0 + ni * 16 + (lane & 15);
    float bb = be[n];
#pragma unroll
    for (int mi = 0; mi < 4; ++mi) {
      int mbase = m0 + mi * 16 + (lane >> 4) * 4;
#pragma unroll
      for (int q = 0; q < 4; ++q)
        apre[(size_t)(mbase + q) * NLAT + n] = acc[mi][ni][q] + bb;
    }
  }
}

// ---------------- f32 fallback GEMM (round-1, verified) ----------------
__global__ __launch_bounds__(256) void k_encgemm_f32(
    const float* __restrict__ x, const float* __restrict__ bvec,
    const float* __restrict__ We, const float* __restrict__ be,
    float* __restrict__ apre) {
  __shared__ float As[BK][LDT];
  __shared__ float Bs[BK][LDT];
  const int t = threadIdx.x;
  const int m0 = blockIdx.x * BM;
  const int n0 = blockIdx.y * BN;
  const int lane = t & 63, wave = t >> 6;
  const int cn = ((wave & 1) * 8 + (lane & 7)) * 8;
  const int cm = ((wave >> 1) * 8 + (lane >> 3)) * 8;
  float acc[8][8] = {};
  const float* xb = x + (size_t)m0 * NIN;
  const float* wb = We + (size_t)n0 * NIN;
  for (int k0 = 0; k0 < NIN; k0 += BK) {
#pragma unroll
    for (int i = 0; i < 2; ++i) {
      int e = t + i * 256;
      int row = e >> 2, q = e & 3;
      float4 bv = *(const float4*)(bvec + k0 + q * 4);
      float4 av = *(const float4*)(xb + (size_t)row * NIN + k0 + q * 4);
      av.x -= bv.x; av.y -= bv.y; av.z -= bv.z; av.w -= bv.w;
      As[q * 4 + 0][row] = av.x; As[q * 4 + 1][row] = av.y;
      As[q * 4 + 2][row] = av.z; As[q * 4 + 3][row] = av.w;
      float4 wv = *(const float4*)(wb + (size_t)row * NIN + k0 + q * 4);
      Bs[q * 4 + 0][row] = wv.x; Bs[q * 4 + 1][row] = wv.y;
      Bs[q * 4 + 2][row] = wv.z; Bs[q * 4 + 3][row] = wv.w;
    }
    __syncthreads();
#pragma unroll
    for (int kk = 0; kk < BK; ++kk) {
      float a0[8], b0[8];
      *(float4*)&a0[0] = *(const float4*)&As[kk][cm];
      *(float4*)&a0[4] = *(const float4*)&As[kk][cm + 4];
      *(float4*)&b0[0] = *(const float4*)&Bs[kk][cn];
      *(float4*)&b0[4] = *(const float4*)&Bs[kk][cn + 4];
#pragma unroll
      for (int i = 0; i < 8; ++i)
#pragma unroll
        for (int j = 0; j < 8; ++j)
          acc[i][j] = fmaf(a0[i], b0[j], acc[i][j]);
    }
    __syncthreads();
  }
  float bb[8];
  *(float4*)&bb[0] = *(const float4*)(be + n0 + cn);
  *(float4*)&bb[4] = *(const float4*)(be + n0 + cn + 4);
#pragma unroll
  for (int i = 0; i < 8; ++i) {
    float4 v0 = make_float4(acc[i][0] + bb[0], acc[i][1] + bb[1],
                            acc[i][2] + bb[2], acc[i][3] + bb[3]);
    float4 v1 = make_float4(acc[i][4] + bb[4], acc[i][5] + bb[5],
                            acc[i][6] + bb[6], acc[i][7] + bb[7]);
    float* orow = apre + (size_t)(m0 + cm + i) * NLAT + n0 + cn;
    *(float4*)orow = v0;
    *(float4*)(orow + 4) = v1;
  }
}

// ---------------- zero fill ----------------
__global__ void k_zero(float4* __restrict__ p, int n4) {
  int stride = gridDim.x * blockDim.x;
  for (int i = blockIdx.x * blockDim.x + threadIdx.x; i < n4; i += stride)
    p[i] = make_float4(0.f, 0.f, 0.f, 0.f);
}

// ---------------- mask scatter ----------------
__global__ void k_scatter_mask(const int* __restrict__ wsIdx,
                               const int* __restrict__ wsCnt,
                               float* __restrict__ mask) {
  int r = blockIdx.x, t = threadIdx.x;
  if (t < wsCnt[r]) mask[(size_t)r * NLAT + wsIdx[r * MAIN_CAP + t]] = 1.0f;
}

// ---------------- find boundary bin for rank kk ----------------
__device__ void find_bin(int* hist, unsigned* csuf, int* tmp, int t, int kk,
                         int& bin, int& above, int& kke) {
  if (t < 256) {
    unsigned c = 0;
#pragma unroll
    for (int i = 0; i < 16; ++i) c += (unsigned)hist[t * 16 + i];
    csuf[t] = c;
  }
  __syncthreads();
  for (int off = 1; off < 256; off <<= 1) {
    unsigned add = 0;
    if (t < 256 && t + off < 256) add = csuf[t + off];
    __syncthreads();
    if (t < 256) csuf[t] += add;
    __syncthreads();
  }
  int total = (int)csuf[0];
  int k2 = kk < total ? kk : total;
  kke = k2;
  if (k2 <= 0) { bin = -1; above = 0; return; }
  if (t < 256) {
    if (csuf[t] >= (unsigned)k2 && (t == 255 || csuf[t + 1] < (unsigned)k2))
      tmp[0] = t;
  }
  __syncthreads();
  int cstar = tmp[0];
  if (t == 0) {
    int ab = (cstar == 255) ? 0 : (int)csuf[cstar + 1];
    int bb = cstar * 16 + 15;
    for (int i2 = 15; i2 >= 0; --i2) {
      int h = hist[cstar * 16 + i2];
      if (ab + h >= k2) { bb = cstar * 16 + i2; break; }
      ab += h;
    }
    tmp[1] = bb; tmp[2] = ab;
  }
  __syncthreads();
  bin = tmp[1]; above = tmp[2];
}

// ------------- per-row: LDS-staged topk (main + aux) + decode ----
__global__ __launch_bounds__(1024) void k_select(
    const float* __restrict__ apre, const float* __restrict__ x,
    const float* __restrict__ bvec, const float* __restrict__ We,
    const float* __restrict__ be, const int* __restrict__ miss,
    const int* __restrict__ kptr, const int* __restrict__ akptr,
    float* __restrict__ alpha, float* __restrict__ xhat,
    float* __restrict__ auxo, const __bf16* __restrict__ Wt,
    const float* __restrict__ Wd, int* __restrict__ wsIdx,
    int* __restrict__ wsCnt) {
  extern __shared__ char smem[];
  float* row      = (float*)smem;                     // 98304
  int* hist       = (int*)(smem + 98304);             // 16384
  unsigned* dead  = (unsigned*)(smem + 114688);       // 3072
  unsigned* csuf  = (unsigned*)(smem + 117760);       // 1024
  int* sIdx       = (int*)(smem + 118784);            // 256
  float* sVal     = (float*)(smem + 119040);          // 256
  int* ctrl       = (int*)(smem + 119296);            // 128  (total 119424)
  // aliases (lifetime-disjoint with hist / csuf)
  int* aIdx       = (int*)(smem + 98304);             // hist[0..4K)
  float* aVal     = (float*)(smem + 98304 + 4096);    // hist[4K..8K)
  unsigned* candU = (unsigned*)(smem + 98304 + 8192); // hist[8K..10K)
  int* candIdx    = (int*)(smem + 98304 + 10240);     // hist[10K..12K)
  double* bandV   = (double*)(smem + 117760);         // csuf[0..512)
  int* bandIdx    = (int*)(smem + 117760 + 512);      // csuf[512..768)
  unsigned char* bandSel = (unsigned char*)(smem + 117760 + 768);

  const int t = threadIdx.x;
  const int r = blockIdx.x;
  const int lane = t & 63, wave = t >> 6;
  const float* rowg = apre + (size_t)r * NLAT;

  if (t == 0) { ctrl[5] = 0; ctrl[6] = 0; }
  for (int i = t; i < HBINS; i += SEL_T) hist[i] = 0;
  __syncthreads();
  // ---- load row -> LDS + main hist + dead bitmask
  for (int i = 0; i < 6; ++i) {
    int j4 = i * SEL_T + t;
    float4 v = *(const float4*)(rowg + j4 * 4);
    *(float4*)(row + j4 * 4) = v;
    atomicAdd(&hist[fkey(v.x) >> 20], 1);
    atomicAdd(&hist[fkey(v.y) >> 20], 1);
    atomicAdd(&hist[fkey(v.z) >> 20], 1);
    atomicAdd(&hist[fkey(v.w) >> 20], 1);
  }
  for (int i = 0; i < 24; ++i) {
    int base = i * SEL_T + wave * 64;
    unsigned long long bm = __ballot(miss[base + lane] >= 1);
    if (lane == 0) {
      dead[base >> 5] = (unsigned)bm;
      dead[(base >> 5) + 1] = (unsigned)(bm >> 32);
    }
  }
  __syncthreads();

  int kmain = kptr[0];  if (kmain > MAIN_CAP) kmain = MAIN_CAP;
  int kaux  = akptr[0]; if (kaux > AUX_CAP)  kaux  = AUX_CAP;

  for (int pass = 0; pass < 2; ++pass) {
    const bool isMain = (pass == 0);
    const int kreq = isMain ? kmain : kaux;
    if (!isMain) {  // rebuild hist with dead filter
      for (int i = t; i < HBINS; i += SEL_T) hist[i] = 0;
      __syncthreads();
      for (int i = 0; i < 24; ++i) {
        int j = i * SEL_T + t;
        if ((dead[j >> 5] >> (j & 31)) & 1)
          atomicAdd(&hist[fkey(row[j]) >> 20], 1);
      }
      __syncthreads();
    }
    int b1, above, kke;
    find_bin(hist, csuf, ctrl + 8, t, kreq, b1, above, kke);
    if (kke <= 0) { __syncthreads(); continue; }
    int need = kke - above;

    // candidates in boundary bin
    if (t == 0) ctrl[0] = 0;
    __syncthreads();
    for (int i = 0; i < 24; ++i) {
      int j = i * SEL_T + t;
      if (!isMain && !((dead[j >> 5] >> (j & 31)) & 1)) continue;
      unsigned u = fkey(row[j]);
      if ((int)(u >> 20) == b1) {
        int p = atomicAdd(&ctrl[0], 1);
        if (p < CAND_CAP) { candU[p] = u; candIdx[p] = j; }
      }
    }
    __syncthreads();
    int cc = ctrl[0]; if (cc > CAND_CAP) cc = CAND_CAP;
    if (t < cc) {  // exact rank -> kth largest key
      unsigned ui = candU[t]; int ii = candIdx[t];
      int rank = 0;
      for (int q = 0; q < cc; ++q) {
        unsigned uq = candU[q];
        if (uq > ui || (uq == ui && candIdx[q] < ii)) ++rank;
      }
      if (rank == need - 1) ctrl[1] = (int)ui;
    }
    __syncthreads();
    float Vk = keyinv((unsigned)ctrl[1]);
    float eps = 3e-4f + 3e-4f * fabsf(Vk);
    float hi = Vk + eps, lo = Vk - eps;
    if (t == 0) { ctrl[2] = 0; ctrl[3] = 0; }
    __syncthreads();
    // band collect + strict-above count
    for (int i = 0; i < 24; ++i) {
      int j = i * SEL_T + t;
      if (!isMain && !((dead[j >> 5] >> (j & 31)) & 1)) continue;
      float v = row[j];
      if (v > hi) atomicAdd(&ctrl[2], 1);
      else if (v >= lo) {
        int p = atomicAdd(&ctrl[3], 1);
        if (p < BAND_CAP) bandIdx[p] = j;
      }
    }
    __syncthreads();
    int nab = ctrl[2];
    int bc = ctrl[3]; if (bc > BAND_CAP) bc = BAND_CAP;
    int needB = kke - nab;
    if (t < bc) {  // exact f64 dot for boundary members
      int j = bandIdx[t];
      const float* wrow = We + (size_t)j * NIN;
      const float* xrow = x + (size_t)r * NIN;
      double s0 = 0.0, s1 = 0.0, s2 = 0.0, s3 = 0.0;
      for (int kx = 0; kx < NIN; kx += 4) {
        s0 += ((double)xrow[kx]   - (double)bvec[kx])   * (double)wrow[kx];
        s1 += ((double)xrow[kx+1] - (double)bvec[kx+1]) * (double)wrow[kx+1];
        s2 += ((double)xrow[kx+2] - (double)bvec[kx+2]) * (double)wrow[kx+2];
        s3 += ((double)xrow[kx+3] - (double)bvec[kx+3]) * (double)wrow[kx+3];
      }
      bandV[t] = ((s0 + s1) + (s2 + s3)) + (double)be[j];
    }
    __syncthreads();
    if (t < bc) {
      double vi = bandV[t]; int ii = bandIdx[t];
      double tie = fabs(vi) * 4e-8 + 1e-12;
      int rank = 0;
      for (int q = 0; q < bc; ++q) {
        double d = bandV[q] - vi;
        bool g = (fabs(d) <= tie) ? (bandIdx[q] < ii) : (d > 0.0);
        if (g) ++rank;
      }
      bandSel[t] = (rank < needB) ? 1 : 0;
    }
    if (t == 0) ctrl[4] = 0;
    __syncthreads();
    // emit
    for (int i = 0; i < 24; ++i) {
      int j = i * SEL_T + t;
      if (!isMain && !((dead[j >> 5] >> (j & 31)) & 1)) continue;
      float v = row[j];
      bool sel = (v > hi);
      if (!sel && v >= lo) {
        for (int m2 = 0; m2 < bc; ++m2)
          if (bandIdx[m2] == j) { sel = (bandSel[m2] != 0); break; }
      }
      if (sel && v != 0.0f) {
        int p = atomicAdd(&ctrl[4], 1);
        if (isMain) {
          if (p < MAIN_CAP) {
            sIdx[p] = j; sVal[p] = v;
            alpha[(size_t)r * NLAT + j] = v;
            wsIdx[r * MAIN_CAP + p] = j;
          }
        } else {
          if (p < AUX_CAP) { aIdx[p] = j; aVal[p] = v; }
        }
      }
    }
    __syncthreads();
    if (t == 0) {
      int c = ctrl[4];
      if (isMain) { ctrl[5] = c > MAIN_CAP ? MAIN_CAP : c; wsCnt[r] = ctrl[5]; }
      else ctrl[6] = c > AUX_CAP ? AUX_CAP : c;
    }
    __syncthreads();
  }

  // ---- decode: xhat = sum sVal*Wdec[:,sIdx] + b ; auxo likewise
  int kc = ctrl[5], ac = ctrl[6];
  if (Wt) {
    if (t < NIN / 2) {
      float m0 = 0.f, m1 = 0.f, a0 = 0.f, a1 = 0.f;
      for (int i = 0; i < kc; ++i) {
        float v = sVal[i];
        bf16x2 w = *(const bf16x2*)(Wt + (size_t)sIdx[i] * NIN + 2 * t);
        m0 = fmaf(v, (float)w[0], m0); m1 = fmaf(v, (float)w[1], m1);
      }
#pragma unroll 4
      for (int i = 0; i < ac; ++i) {
        float v = aVal[i];
        bf16x2 w = *(const bf16x2*)(Wt + (size_t)aIdx[i] * NIN + 2 * t);
        a0 = fmaf(v, (float)w[0], a0); a1 = fmaf(v, (float)w[1], a1);
      }
      float b0 = bvec[2 * t], b1 = bvec[2 * t + 1];
      *(float2*)(xhat + (size_t)r * NIN + 2 * t) = make_float2(m0 + b0, m1 + b1);
      *(float2*)(auxo + (size_t)r * NIN + 2 * t) = make_float2(a0 + b0, a1 + b1);
    }
  } else {
    if (t < NIN) {
      float m0 = 0.f, a0 = 0.f;
      for (int i = 0; i < kc; ++i)
        m0 = fmaf(sVal[i], Wd[(size_t)t * NLAT + sIdx[i]], m0);
      for (int i = 0; i < ac; ++i)
        a0 = fmaf(aVal[i], Wd[(size_t)t * NLAT + aIdx[i]], a0);
      float bb = bvec[t];
      xhat[(size_t)r * NIN + t] = m0 + bb;
      auxo[(size_t)r * NIN + t] = a0 + bb;
    }
  }
}

extern "C" void kernel_launch(void* const* d_in, const int* in_sizes, int n_in,
                              void* d_out, int out_size, void* d_ws, size_t ws_size,
                              hipStream_t stream) {
  const float* x  = (const float*)d_in[0];
  const float* bv = (const float*)d_in[1];
  const float* We = (const float*)d_in[2];
  const float* be = (const float*)d_in[3];
  const float* Wd = (const float*)d_in[4];
  const int* miss = (const int*)d_in[5];
  const int* kp   = (const int*)d_in[6];
  const int* akp  = (const int*)d_in[7];

  float* out   = (float*)d_out;
  float* xhat  = out;                          // [4096 x 768]
  float* alpha = out + (size_t)3145728;        // [4096 x 24576]
  float* apre  = out + (size_t)103809024;      // fired_mask region; alpha_pre scratch
  float* auxo  = out + (size_t)204472320;      // [4096 x 768]

  // ws layout: [0,1M) main idx lists; [1M,1M+16K) counts; [2M) Wt bf16 (36M);
  // then A2 (18M) and B2 (108M)
  int*   wsIdx = (int*)d_ws;
  int*   wsCnt = (int*)((char*)d_ws + (1u << 20));
  size_t offWt = (size_t)2 << 20;
  size_t offA2 = offWt + (size_t)NLAT * NIN * 2;      // + 36 MiB
  size_t offB2 = offA2 + (size_t)NB * K2 * 2;         // + 18 MiB
  size_t needFull = offB2 + (size_t)NLAT * K2 * 2;    // + 108 MiB = ~164 MiB
  bool haveWt   = ws_size >= offA2;
  bool haveFull = ws_size >= needFull;
  __bf16* Wt = haveWt ? (__bf16*)((char*)d_ws + offWt) : nullptr;
  __bf16* A2 = (__bf16*)((char*)d_ws + offA2);
  __bf16* B2 = (__bf16*)((char*)d_ws + offB2);

  if (haveFull) {
    k_pack_a<<<dim3(32, KT2), 256, 0, stream>>>(x, bv, A2);
    k_pack_b<<<dim3(192, KT2), 256, 0, stream>>>(We, B2);
  }
  if (haveWt)
    k_transpose<<<dim3(NLAT / 32, NIN / 32), dim3(32, 8), 0, stream>>>(Wd, Wt);

  if (haveFull)
    k_gemm_bf16<<<dim3(32, 192), 256, 0, stream>>>(A2, B2, be, apre);
  else
    k_encgemm_f32<<<dim3(NB / BM, NLAT / BN), 256, 0, stream>>>(x, bv, We, be, apre);

  k_zero<<<2048, 256, 0, stream>>>((float4*)alpha, 25165824);
  k_select<<<NB, SEL_T, 119424, stream>>>(apre, x, bv, We, be, miss, kp, akp,
                                          alpha, xhat, auxo, Wt, Wd, wsIdx, wsCnt);
  k_zero<<<2048, 256, 0, stream>>>((float4*)apre, 25165824);  // mask region
  k_scatter_mask<<<NB, 64, 0, stream>>>(wsIdx, wsCnt, apre);
}